// Round 8
// baseline (672.891 us; speedup 1.0000x reference)
//
#include <hip/hip_runtime.h>

typedef unsigned int u32;
typedef unsigned short u16;
typedef __bf16 bf16x8 __attribute__((ext_vector_type(8)));
typedef float f32x16 __attribute__((ext_vector_type(16)));
typedef u32 u32x4 __attribute__((ext_vector_type(4)));

// ---------- helpers ----------
__device__ __forceinline__ u16 f2bf(float f) {
  u32 u = __float_as_uint(f);
  u32 r = (u + 0x7FFFu + ((u >> 16) & 1u)) >> 16;
  return (u16)r;
}
__device__ __forceinline__ float bf2f(u16 h) {
  return __uint_as_float((u32)h << 16);
}
__device__ __forceinline__ u32 pack2bf(float a, float b) {
  return (u32)f2bf(a) | ((u32)f2bf(b) << 16);
}
__device__ __forceinline__ float fast_tanh(float x) {
  float e = __expf(2.0f * x);
  return 1.0f - 2.0f * __builtin_amdgcn_rcpf(e + 1.0f);
}

// bilinear interp matching jnp.searchsorted(side='right')-1 with clamping
__device__ __forceinline__ float inter2d_d(const float* xs, const float* ys,
                                           const float* tb, float xq, float yq) {
  xq = fminf(fmaxf(xq, xs[0]), xs[8]);
  yq = fminf(fmaxf(yq, ys[0]), ys[13]);
  int i = 0, j = 0;
#pragma unroll
  for (int k = 1; k <= 8; ++k) if (xq >= xs[k]) i = k;
#pragma unroll
  for (int k = 1; k <= 13; ++k) if (yq >= ys[k]) j = k;
  if (i > 7) i = 7;
  if (j > 12) j = 12;
  float x0 = xs[i], x1 = xs[i + 1], y0 = ys[j], y1 = ys[j + 1];
  float tx = (xq - x0) / (x1 - x0);
  float ty = (yq - y0) / (y1 - y0);
  float f00 = tb[i * 14 + j], f01 = tb[i * 14 + j + 1];
  float f10 = tb[(i + 1) * 14 + j], f11 = tb[(i + 1) * 14 + j + 1];
  return f00 * (1 - tx) * (1 - ty) + f10 * tx * (1 - ty) +
         f01 * (1 - tx) * ty + f11 * tx * ty;
}

// ---------- kernel 1: moments of u (4 means + 10 second moments) ----------
__global__ void stats1_kernel(const float* __restrict__ x,
                              const float* __restrict__ tsg,
                              const float* __restrict__ teg,
                              const float* __restrict__ tbg,
                              float* __restrict__ mom) {
  __shared__ float ts[9], te[14], tb[126], bacc[14];
  int t = threadIdx.x;
  if (t < 9) ts[t] = tsg[t];
  if (t < 14) { te[t] = teg[t]; bacc[t] = 0.f; }
  if (t < 126) tb[t] = tbg[t];
  __syncthreads();
  const float* xr = x + (size_t)(blockIdx.x * 256 + t) * 15;
  float amb = xr[1], inc = xr[8];
  float u0 = inter2d_d(ts, te, tb, xr[2], amb) - inc;
  float u1 = inter2d_d(ts, te, tb, xr[3], amb) - inc;
  float u2 = amb, u3 = xr[9] - xr[10];
  float v[14] = {u0, u1, u2, u3,
                 u0 * u0, u0 * u1, u0 * u2, u0 * u3,
                 u1 * u1, u1 * u2, u1 * u3,
                 u2 * u2, u2 * u3, u3 * u3};
#pragma unroll
  for (int i = 0; i < 14; ++i) {
    float s = v[i];
    s += __shfl_xor(s, 32); s += __shfl_xor(s, 16); s += __shfl_xor(s, 8);
    s += __shfl_xor(s, 4);  s += __shfl_xor(s, 2);  s += __shfl_xor(s, 1);
    v[i] = s;
  }
  if ((t & 63) == 0)
    for (int i = 0; i < 14; ++i) atomicAdd(&bacc[i], v[i]);
  __syncthreads();
  if (t < 14) atomicAdd(&mom[t], bacc[t]);
}

// ---------- kernel 2: fold BN1 into the layer-1 MFMA A-frag image ----------
// Error-compensated; per j two 16B frags (hi=0/1):
//  hi0: [bf(a0..a3), c1_hi, da0, da1, da2]
//  hi1: [bf(a0..a3), c1_lo, da3, 0, 0]
__global__ void prep1_kernel(const float* __restrict__ mom,
                             const float* __restrict__ w1,
                             const float* __restrict__ g1,
                             const float* __restrict__ be1,
                             unsigned char* __restrict__ a1img, float invB) {
  int j = threadIdx.x;  // 512
  float m0 = mom[0] * invB, m1 = mom[1] * invB, m2 = mom[2] * invB, m3 = mom[3] * invB;
  float C00 = mom[4]  * invB - m0 * m0, C01 = mom[5]  * invB - m0 * m1;
  float C02 = mom[6]  * invB - m0 * m2, C03 = mom[7]  * invB - m0 * m3;
  float C11 = mom[8]  * invB - m1 * m1, C12 = mom[9]  * invB - m1 * m2;
  float C13 = mom[10] * invB - m1 * m3, C22 = mom[11] * invB - m2 * m2;
  float C23 = mom[12] * invB - m2 * m3, C33 = mom[13] * invB - m3 * m3;
  float a = w1[j], b = w1[512 + j], c = w1[1024 + j], d = w1[1536 + j];
  float var = a * a * C00 + b * b * C11 + c * c * C22 + d * d * C33 +
              2.f * (a * b * C01 + a * c * C02 + a * d * C03 +
                     b * c * C12 + b * d * C13 + c * d * C23);
  float s1 = g1[j] * rsqrtf(fmaxf(var, 0.f) + 1e-5f);
  float a0 = a * s1, a1 = b * s1, a2 = c * s1, a3 = d * s1;
  float c1j = be1[j] - (m0 * a + m1 * b + m2 * c + m3 * d) * s1;
  u16 ba0 = f2bf(a0), ba1 = f2bf(a1), ba2 = f2bf(a2), ba3 = f2bf(a3);
  u16 da0 = f2bf(a0 - bf2f(ba0)), da1 = f2bf(a1 - bf2f(ba1));
  u16 da2 = f2bf(a2 - bf2f(ba2)), da3 = f2bf(a3 - bf2f(ba3));
  u16 c1h = f2bf(c1j);
  u16 c1l = f2bf(c1j - bf2f(c1h));
  u32 p01 = (u32)ba0 | ((u32)ba1 << 16);
  u32 p23 = (u32)ba2 | ((u32)ba3 << 16);
  uint4* img = (uint4*)a1img;
  img[j * 2]     = make_uint4(p01, p23, (u32)c1h | ((u32)da0 << 16),
                              (u32)da1 | ((u32)da2 << 16));
  img[j * 2 + 1] = make_uint4(p01, p23, (u32)c1l | ((u32)da3 << 16), 0u);
}

// ---------- kernel 3: w2 -> bf16, frag-contiguous image ----------
// chunk index q = G*512 + n (G = global K-octet 0..63); content = w2[G*8+e][n]
__global__ void transpose_w2(const float* __restrict__ w2,
                             unsigned char* __restrict__ w2ts) {
  int q = blockIdx.x * 256 + threadIdx.x;  // 0..32767
  int n = q & 511;
  int kb = (q >> 9) * 8;
  u32 pk[4];
#pragma unroll
  for (int e = 0; e < 8; e += 2) {
    u16 a = f2bf(w2[(size_t)(kb + e) * 512 + n]);
    u16 b = f2bf(w2[(size_t)(kb + e + 1) * 512 + n]);
    pk[e >> 1] = (u32)a | ((u32)b << 16);
  }
  *(uint4*)(w2ts + (size_t)q * 16) = make_uint4(pk[0], pk[1], pk[2], pk[3]);
}

// ---------- kernel 5: fold BN2 into s2,c2 (b2 cancels exactly) ----------
__global__ void prep2_kernel(const float* __restrict__ stat2,
                             const float* __restrict__ g2,
                             const float* __restrict__ be2,
                             float* __restrict__ s2, float* __restrict__ c2,
                             float invB) {
  int j = threadIdx.x;
  float mu = stat2[j] * invB;
  float ex2 = stat2[512 + j] * invB;
  float var = fmaxf(ex2 - mu * mu, 0.f);
  float s = g2[j] * rsqrtf(var + 1e-5f);
  s2[j] = s; c2[j] = be2[j] - mu * s;
}

// ---------- kernels 4 & 6: fused t1 + GEMM(t1 @ w2) ----------
// 256 thr = 4 waves; block = 64 rows x 256 cols (col-half via blockIdx&1).
// Wave tile 64x64 (acc=64/lane). t1 produced in 64-j slabs (8KB dbuf) via
// layer-1 MFMA, 1 produce-unit/wave/slab. B direct L2->VGPR pipelined a FULL
// SLAB (4 k-steps) ahead: slot = s, refilled right after consumption.
// 4 waves/SIMD x 4-step depth ==> ~500 cyc of issue-side latency cover.
template <int EPI>
__global__ __launch_bounds__(256, 4) void gemm_fused(
    const float* __restrict__ x, const float* __restrict__ tsg,
    const float* __restrict__ teg, const float* __restrict__ tbg,
    const unsigned char* __restrict__ a1img,
    const unsigned char* __restrict__ w2ts, float* __restrict__ stat2,
    const float* __restrict__ s2g, const float* __restrict__ c2g,
    const float* __restrict__ w3g, const float* __restrict__ b3g,
    float* __restrict__ out) {
  __shared__ __align__(16) unsigned char sm_t1[2][8192];  // slab: (c*64+m)*16, c=0..7
  __shared__ __align__(16) float sm_u[64][4];
  __shared__ float sm_ts[9], sm_te[14], sm_tb[126];

  const int t = threadIdx.x;
  const int w = t >> 6, l = t & 63;
  const int hi = l >> 5, ln = l & 31;
  const int rb = blockIdx.x >> 1;
  const int ch = blockIdx.x & 1;
  const int r0 = rb * 64;
  const int N0 = ch * 256;
  const int ph = rb & 7;        // slab stagger phase
  const int jt = w & 1;         // produce: j-tile within slab
  const int rg = w >> 1;        // produce: row-group (rows rg*32..)

  if (t < 9) sm_ts[t] = tsg[t];
  if (t < 14) sm_te[t] = teg[t];
  if (t < 126) sm_tb[t] = tbg[t];
  __syncthreads();

  if (t < 64) {
    const float* xr = x + (size_t)(r0 + t) * 15;
    float amb = xr[1], inc = xr[8];
    sm_u[t][0] = inter2d_d(sm_ts, sm_te, sm_tb, xr[2], amb) - inc;
    sm_u[t][1] = inter2d_d(sm_ts, sm_te, sm_tb, xr[3], amb) - inc;
    sm_u[t][2] = amb;
    sm_u[t][3] = xr[9] - xr[10];
  }
  __syncthreads();

  // u B-frag for layer-1 MFMA (rows rg*32+ln):
  // hi0: [bf(u0..u3), 1, bf(u0), bf(u1), bf(u2)]
  // hi1: [du0..du3,   1, bf(u3), 0, 0]
  bf16x8 uf;
  {
    float4 uv = *(const float4*)&sm_u[rg * 32 + ln][0];
    u16 b0_ = f2bf(uv.x), b1_ = f2bf(uv.y), b2_ = f2bf(uv.z), b3_ = f2bf(uv.w);
    u32x4 uq;
    if (hi == 0) {
      uq[0] = (u32)b0_ | ((u32)b1_ << 16);
      uq[1] = (u32)b2_ | ((u32)b3_ << 16);
      uq[2] = 0x00003F80u | ((u32)b0_ << 16);
      uq[3] = (u32)b1_ | ((u32)b2_ << 16);
    } else {
      u16 d0 = f2bf(uv.x - bf2f(b0_)), d1 = f2bf(uv.y - bf2f(b1_));
      u16 d2 = f2bf(uv.z - bf2f(b2_)), d3 = f2bf(uv.w - bf2f(b3_));
      uq[0] = (u32)d0 | ((u32)d1 << 16);
      uq[1] = (u32)d2 | ((u32)d3 << 16);
      uq[2] = 0x00003F80u | ((u32)b3_ << 16);
      uq[3] = 0u;
    }
    uf = __builtin_bit_cast(bf16x8, uq);
  }

  // produce t1 slab sl (global 0..7) into dst: wave w -> j-tile jt, row-group rg.
  auto produce = [&](int sl, unsigned char* dst) {
    bf16x8 af = *(const bf16x8*)(a1img +
        ((size_t)(sl * 64 + jt * 32 + ln) * 32 + hi * 16));
    f32x16 z = {};
    f32x16 d = __builtin_amdgcn_mfma_f32_32x32x16_bf16(af, uf, z, 0, 0, 0);
#pragma unroll
    for (int q = 0; q < 4; ++q) {
      u32 plo = pack2bf(fast_tanh(d[q * 4 + 0]), fast_tanh(d[q * 4 + 1]));
      u32 phi = pack2bf(fast_tanh(d[q * 4 + 2]), fast_tanh(d[q * 4 + 3]));
      *(uint2*)(dst + ((size_t)(jt * 4 + q) * 1024 + (rg * 32 + ln) * 16 + hi * 8)) =
          make_uint2(plo, phi);
    }
  };

  // B loads for linear step p in [0,32): slot bb[p&3] (== s)
  auto loadB = [&](uint4* dst, int p) {
    int kt = (ph * 4 + p) & 31;
    const uint4* src = (const uint4*)w2ts +
        ((size_t)(2 * kt + hi) * 512 + N0 + w * 64 + ln);
    dst[0] = src[0];
    dst[1] = src[32];
  };

  f32x16 acc[4];  // [mf*2+nf]
#pragma unroll
  for (int i = 0; i < 4; ++i)
#pragma unroll
    for (int k = 0; k < 16; ++k) acc[i][k] = 0.0f;

  uint4 bb[4][2];
  loadB(bb[0], 0); loadB(bb[1], 1); loadB(bb[2], 2); loadB(bb[3], 3);
  produce(ph, sm_t1[0]);
  __syncthreads();

#pragma unroll 1
  for (int i = 0; i < 8; ++i) {
    const unsigned char* abuf = sm_t1[i & 1];
#pragma unroll
    for (int s = 0; s < 4; ++s) {
      const unsigned char* ab = abuf + (size_t)(2 * s + hi) * 1024 + ln * 16;
      bf16x8 a0 = *(const bf16x8*)(ab);
      bf16x8 a1 = *(const bf16x8*)(ab + 512);  // rows +32
#pragma unroll
      for (int nf = 0; nf < 2; ++nf) {
        bf16x8 bv = __builtin_bit_cast(bf16x8, bb[s][nf]);
        acc[0 + nf] = __builtin_amdgcn_mfma_f32_32x32x16_bf16(a0, bv, acc[0 + nf], 0, 0, 0);
        acc[2 + nf] = __builtin_amdgcn_mfma_f32_32x32x16_bf16(a1, bv, acc[2 + nf], 0, 0, 0);
      }
      if (i < 7) loadB(bb[s], i * 4 + s + 4);  // refill slot a full slab ahead
      if (s == 0 && i < 7) produce((ph + i + 1) & 7, sm_t1[(i + 1) & 1]);
    }
    __syncthreads();
  }

  // C/D layout (32x32x16): col = lane&31, row_in_tile = (k&3) + 8*(k>>2) + 4*hi
  if (EPI == 0) {
#pragma unroll
    for (int nf = 0; nf < 2; ++nf) {
      float s = 0.f, q = 0.f;
#pragma unroll
      for (int mf = 0; mf < 2; ++mf)
#pragma unroll
        for (int k = 0; k < 16; ++k) {
          float v = acc[mf * 2 + nf][k];
          s += v; q += v * v;
        }
      s += __shfl_xor(s, 32); q += __shfl_xor(q, 32);
      if (hi == 0) {
        int col = N0 + w * 64 + nf * 32 + ln;
        atomicAdd(&stat2[col], s);
        atomicAdd(&stat2[512 + col], q);
      }
    }
  } else {
    float sv[2], cv[2], wv[2];
#pragma unroll
    for (int nf = 0; nf < 2; ++nf) {
      int col = N0 + w * 64 + nf * 32 + ln;
      sv[nf] = s2g[col]; cv[nf] = c2g[col]; wv[nf] = w3g[col];
    }
    float* pr = (float*)sm_t1[0];  // [64 rows][4 waves]
#pragma unroll
    for (int mf = 0; mf < 2; ++mf)
#pragma unroll
      for (int k = 0; k < 16; ++k) {
        float v = fast_tanh(acc[mf * 2 + 0][k] * sv[0] + cv[0]) * wv[0] +
                  fast_tanh(acc[mf * 2 + 1][k] * sv[1] + cv[1]) * wv[1];
        v += __shfl_xor(v, 1); v += __shfl_xor(v, 2); v += __shfl_xor(v, 4);
        v += __shfl_xor(v, 8); v += __shfl_xor(v, 16);
        if (ln == 0) {
          int row = mf * 32 + (k & 3) + 8 * (k >> 2) + 4 * hi;
          pr[row * 4 + w] = v;
        }
      }
    __syncthreads();
    if (t < 64) {
      float s = pr[t * 4] + pr[t * 4 + 1] + pr[t * 4 + 2] + pr[t * 4 + 3] +
                0.5f * b3g[0];  // each col-half adds half of b3
      atomicAdd(&out[r0 + t], s);
    }
  }
}

// ---------- launcher ----------
extern "C" void kernel_launch(void* const* d_in, const int* in_sizes, int n_in,
                              void* d_out, int out_size, void* d_ws, size_t ws_size,
                              hipStream_t stream) {
  const float* x   = (const float*)d_in[0];
  const float* ts  = (const float*)d_in[1];
  const float* te  = (const float*)d_in[2];
  const float* tab = (const float*)d_in[3];
  const float* w1  = (const float*)d_in[4];
  const float* g1  = (const float*)d_in[6];
  const float* be1 = (const float*)d_in[7];
  const float* w2  = (const float*)d_in[8];
  const float* g2  = (const float*)d_in[10];
  const float* be2 = (const float*)d_in[11];
  const float* w3  = (const float*)d_in[12];
  const float* b3  = (const float*)d_in[13];
  float* out = (float*)d_out;
  char* ws = (char*)d_ws;

  if (ws_size < (size_t)(32768 + 524288)) return;

  int Bn = in_sizes[0] / 15;  // 262144
  float invB = 1.0f / (float)Bn;

  float* mom   = (float*)(ws + 0);      // 14 f32 (zeroed)
  float* stat2 = (float*)(ws + 64);     // 1024 f32 (zeroed)
  unsigned char* a1img = (unsigned char*)(ws + 4160);  // 16 KB (512 j x 32B)
  float* s2    = (float*)(ws + 20544);  // 512 f32
  float* c2    = (float*)(ws + 22592);  // 512 f32
  unsigned char* w2ts = (unsigned char*)(ws + 32768);  // 512 KB bf16 image

  (void)hipMemsetAsync(ws, 0, 4160, stream);
  (void)hipMemsetAsync(d_out, 0, (size_t)out_size * 4, stream);
  stats1_kernel<<<Bn / 256, 256, 0, stream>>>(x, ts, te, tab, mom);
  prep1_kernel<<<1, 512, 0, stream>>>(mom, w1, g1, be1, a1img, invB);
  transpose_w2<<<128, 256, 0, stream>>>(w2, w2ts);
  gemm_fused<0><<<Bn / 64 * 2, 256, 0, stream>>>(x, ts, te, tab, a1img, w2ts, stat2,
                                                 nullptr, nullptr, nullptr, nullptr, nullptr);
  prep2_kernel<<<1, 512, 0, stream>>>(stat2, g2, be2, s2, c2, invB);
  gemm_fused<1><<<Bn / 64 * 2, 256, 0, stream>>>(x, ts, te, tab, a1img, w2ts, stat2,
                                                 s2, c2, w3, b3, out);
}

// Round 9
// 503.372 us; speedup vs baseline: 1.3368x; 1.3368x over previous
//
#include <hip/hip_runtime.h>

typedef unsigned int u32;
typedef unsigned short u16;
typedef __bf16 bf16x8 __attribute__((ext_vector_type(8)));
typedef float f32x16 __attribute__((ext_vector_type(16)));
typedef u32 u32x4 __attribute__((ext_vector_type(4)));

// ---------- helpers ----------
__device__ __forceinline__ u16 f2bf(float f) {
  u32 u = __float_as_uint(f);
  u32 r = (u + 0x7FFFu + ((u >> 16) & 1u)) >> 16;
  return (u16)r;
}
__device__ __forceinline__ float bf2f(u16 h) {
  return __uint_as_float((u32)h << 16);
}
__device__ __forceinline__ u32 pack2bf(float a, float b) {
  return (u32)f2bf(a) | ((u32)f2bf(b) << 16);
}
__device__ __forceinline__ float fast_tanh(float x) {
  float e = __expf(2.0f * x);
  return 1.0f - 2.0f * __builtin_amdgcn_rcpf(e + 1.0f);
}
__device__ __forceinline__ void glds16(const void* g, void* l) {
  __builtin_amdgcn_global_load_lds(
      (__attribute__((address_space(1))) void*)g,
      (__attribute__((address_space(3))) void*)l, 16, 0, 0);
}

// bilinear interp matching jnp.searchsorted(side='right')-1 with clamping
__device__ __forceinline__ float inter2d_d(const float* xs, const float* ys,
                                           const float* tb, float xq, float yq) {
  xq = fminf(fmaxf(xq, xs[0]), xs[8]);
  yq = fminf(fmaxf(yq, ys[0]), ys[13]);
  int i = 0, j = 0;
#pragma unroll
  for (int k = 1; k <= 8; ++k) if (xq >= xs[k]) i = k;
#pragma unroll
  for (int k = 1; k <= 13; ++k) if (yq >= ys[k]) j = k;
  if (i > 7) i = 7;
  if (j > 12) j = 12;
  float x0 = xs[i], x1 = xs[i + 1], y0 = ys[j], y1 = ys[j + 1];
  float tx = (xq - x0) / (x1 - x0);
  float ty = (yq - y0) / (y1 - y0);
  float f00 = tb[i * 14 + j], f01 = tb[i * 14 + j + 1];
  float f10 = tb[(i + 1) * 14 + j], f11 = tb[(i + 1) * 14 + j + 1];
  return f00 * (1 - tx) * (1 - ty) + f10 * tx * (1 - ty) +
         f01 * (1 - tx) * ty + f11 * tx * ty;
}

// ---------- kernel 1: moments of u ----------
__global__ void stats1_kernel(const float* __restrict__ x,
                              const float* __restrict__ tsg,
                              const float* __restrict__ teg,
                              const float* __restrict__ tbg,
                              float* __restrict__ mom) {
  __shared__ float ts[9], te[14], tb[126], bacc[14];
  int t = threadIdx.x;
  if (t < 9) ts[t] = tsg[t];
  if (t < 14) { te[t] = teg[t]; bacc[t] = 0.f; }
  if (t < 126) tb[t] = tbg[t];
  __syncthreads();
  const float* xr = x + (size_t)(blockIdx.x * 256 + t) * 15;
  float amb = xr[1], inc = xr[8];
  float u0 = inter2d_d(ts, te, tb, xr[2], amb) - inc;
  float u1 = inter2d_d(ts, te, tb, xr[3], amb) - inc;
  float u2 = amb, u3 = xr[9] - xr[10];
  float v[14] = {u0, u1, u2, u3,
                 u0 * u0, u0 * u1, u0 * u2, u0 * u3,
                 u1 * u1, u1 * u2, u1 * u3,
                 u2 * u2, u2 * u3, u3 * u3};
#pragma unroll
  for (int i = 0; i < 14; ++i) {
    float s = v[i];
    s += __shfl_xor(s, 32); s += __shfl_xor(s, 16); s += __shfl_xor(s, 8);
    s += __shfl_xor(s, 4);  s += __shfl_xor(s, 2);  s += __shfl_xor(s, 1);
    v[i] = s;
  }
  if ((t & 63) == 0)
    for (int i = 0; i < 14; ++i) atomicAdd(&bacc[i], v[i]);
  __syncthreads();
  if (t < 14) atomicAdd(&mom[t], bacc[t]);
}

// ---------- kernel 2: fold BN1 into layer-1 MFMA A-frag image (err-comp) ----------
__global__ void prep1_kernel(const float* __restrict__ mom,
                             const float* __restrict__ w1,
                             const float* __restrict__ g1,
                             const float* __restrict__ be1,
                             unsigned char* __restrict__ a1img, float invB) {
  int j = threadIdx.x;  // 512
  float m0 = mom[0] * invB, m1 = mom[1] * invB, m2 = mom[2] * invB, m3 = mom[3] * invB;
  float C00 = mom[4]  * invB - m0 * m0, C01 = mom[5]  * invB - m0 * m1;
  float C02 = mom[6]  * invB - m0 * m2, C03 = mom[7]  * invB - m0 * m3;
  float C11 = mom[8]  * invB - m1 * m1, C12 = mom[9]  * invB - m1 * m2;
  float C13 = mom[10] * invB - m1 * m3, C22 = mom[11] * invB - m2 * m2;
  float C23 = mom[12] * invB - m2 * m3, C33 = mom[13] * invB - m3 * m3;
  float a = w1[j], b = w1[512 + j], c = w1[1024 + j], d = w1[1536 + j];
  float var = a * a * C00 + b * b * C11 + c * c * C22 + d * d * C33 +
              2.f * (a * b * C01 + a * c * C02 + a * d * C03 +
                     b * c * C12 + b * d * C13 + c * d * C23);
  float s1 = g1[j] * rsqrtf(fmaxf(var, 0.f) + 1e-5f);
  float a0 = a * s1, a1 = b * s1, a2 = c * s1, a3 = d * s1;
  float c1j = be1[j] - (m0 * a + m1 * b + m2 * c + m3 * d) * s1;
  u16 ba0 = f2bf(a0), ba1 = f2bf(a1), ba2 = f2bf(a2), ba3 = f2bf(a3);
  u16 da0 = f2bf(a0 - bf2f(ba0)), da1 = f2bf(a1 - bf2f(ba1));
  u16 da2 = f2bf(a2 - bf2f(ba2)), da3 = f2bf(a3 - bf2f(ba3));
  u16 c1h = f2bf(c1j);
  u16 c1l = f2bf(c1j - bf2f(c1h));
  u32 p01 = (u32)ba0 | ((u32)ba1 << 16);
  u32 p23 = (u32)ba2 | ((u32)ba3 << 16);
  uint4* img = (uint4*)a1img;
  img[j * 2]     = make_uint4(p01, p23, (u32)c1h | ((u32)da0 << 16),
                              (u32)da1 | ((u32)da2 << 16));
  img[j * 2 + 1] = make_uint4(p01, p23, (u32)c1l | ((u32)da3 << 16), 0u);
}

// ---------- kernel 3: w2 -> bf16 frag image ----------
__global__ void transpose_w2(const float* __restrict__ w2,
                             unsigned char* __restrict__ w2ts) {
  int q = blockIdx.x * 256 + threadIdx.x;  // 0..32767
  int n = q & 511;
  int kb = (q >> 9) * 8;
  u32 pk[4];
#pragma unroll
  for (int e = 0; e < 8; e += 2) {
    u16 a = f2bf(w2[(size_t)(kb + e) * 512 + n]);
    u16 b = f2bf(w2[(size_t)(kb + e + 1) * 512 + n]);
    pk[e >> 1] = (u32)a | ((u32)b << 16);
  }
  *(uint4*)(w2ts + (size_t)q * 16) = make_uint4(pk[0], pk[1], pk[2], pk[3]);
}

// ---------- kernel 5: fold BN2 ----------
__global__ void prep2_kernel(const float* __restrict__ stat2,
                             const float* __restrict__ g2,
                             const float* __restrict__ be2,
                             float* __restrict__ s2, float* __restrict__ c2,
                             float invB) {
  int j = threadIdx.x;
  float mu = stat2[j] * invB;
  float ex2 = stat2[512 + j] * invB;
  float var = fmaxf(ex2 - mu * mu, 0.f);
  float s = g2[j] * rsqrtf(var + 1e-5f);
  s2[j] = s; c2[j] = be2[j] - mu * s;
}

// ---------- PATH A: produce t1 (bf16, A-frag layout) to global ----------
// 256 thr = 4 waves; block = one 64-row panel at t1g + blockIdx*65536,
// chunk (c*64 + m)*16, c = j-octet 0..63, m = row 0..63.
__global__ __launch_bounds__(256) void produce_t1(
    const float* __restrict__ x, const float* __restrict__ tsg,
    const float* __restrict__ teg, const float* __restrict__ tbg,
    const unsigned char* __restrict__ a1img, unsigned char* __restrict__ t1g) {
  __shared__ __align__(16) float sm_u[64][4];
  __shared__ float sm_ts[9], sm_te[14], sm_tb[126];
  const int t = threadIdx.x;
  const int w = t >> 6, l = t & 63;
  const int hi = l >> 5, ln = l & 31;
  const int r0 = blockIdx.x * 64;

  if (t < 9) sm_ts[t] = tsg[t];
  if (t < 14) sm_te[t] = teg[t];
  if (t < 126) sm_tb[t] = tbg[t];
  __syncthreads();
  if (t < 64) {
    const float* xr = x + (size_t)(r0 + t) * 15;
    float amb = xr[1], inc = xr[8];
    sm_u[t][0] = inter2d_d(sm_ts, sm_te, sm_tb, xr[2], amb) - inc;
    sm_u[t][1] = inter2d_d(sm_ts, sm_te, sm_tb, xr[3], amb) - inc;
    sm_u[t][2] = amb;
    sm_u[t][3] = xr[9] - xr[10];
  }
  __syncthreads();

  bf16x8 uf[2];
#pragma unroll
  for (int rg = 0; rg < 2; ++rg) {
    float4 uv = *(const float4*)&sm_u[rg * 32 + ln][0];
    u16 b0_ = f2bf(uv.x), b1_ = f2bf(uv.y), b2_ = f2bf(uv.z), b3_ = f2bf(uv.w);
    u32x4 uq;
    if (hi == 0) {
      uq[0] = (u32)b0_ | ((u32)b1_ << 16);
      uq[1] = (u32)b2_ | ((u32)b3_ << 16);
      uq[2] = 0x00003F80u | ((u32)b0_ << 16);
      uq[3] = (u32)b1_ | ((u32)b2_ << 16);
    } else {
      u16 d0 = f2bf(uv.x - bf2f(b0_)), d1 = f2bf(uv.y - bf2f(b1_));
      u16 d2 = f2bf(uv.z - bf2f(b2_)), d3 = f2bf(uv.w - bf2f(b3_));
      uq[0] = (u32)d0 | ((u32)d1 << 16);
      uq[1] = (u32)d2 | ((u32)d3 << 16);
      uq[2] = 0x00003F80u | ((u32)b3_ << 16);
      uq[3] = 0u;
    }
    uf[rg] = __builtin_bit_cast(bf16x8, uq);
  }

  unsigned char* pan = t1g + (size_t)blockIdx.x * 65536;
#pragma unroll
  for (int i = 0; i < 4; ++i) {
    int jt = w * 4 + i;  // j-tile 0..15
    bf16x8 af = *(const bf16x8*)(a1img + ((size_t)(jt * 32 + ln) * 32 + hi * 16));
#pragma unroll
    for (int rg = 0; rg < 2; ++rg) {
      f32x16 z = {};
      f32x16 d = __builtin_amdgcn_mfma_f32_32x32x16_bf16(af, uf[rg], z, 0, 0, 0);
#pragma unroll
      for (int q = 0; q < 4; ++q) {
        u32 plo = pack2bf(fast_tanh(d[q * 4 + 0]), fast_tanh(d[q * 4 + 1]));
        u32 phi = pack2bf(fast_tanh(d[q * 4 + 2]), fast_tanh(d[q * 4 + 3]));
        *(uint2*)(pan + ((size_t)((jt * 4 + q) * 64 + rg * 32 + ln) * 16 + hi * 8)) =
            make_uint2(plo, phi);
      }
    }
  }
}

// ---------- PATH A: pure GEMM t1 @ w2 ----------
// 512 thr = 8 waves; block 64 rows x 512 cols; wave tile 64x64 (acc=64/lane).
// A staged once to LDS (64KB); barrier-free fully-unrolled K-loop; B direct
// L2->VGPR 4-deep pipeline; per-block K stagger.
template <int EPI>
__global__ __launch_bounds__(512, 4) void gemm_pure(
    const unsigned char* __restrict__ t1g,
    const unsigned char* __restrict__ w2ts, float* __restrict__ stat2,
    const float* __restrict__ s2g, const float* __restrict__ c2g,
    const float* __restrict__ w3g, const float* __restrict__ b3g,
    float* __restrict__ out) {
  __shared__ __align__(16) unsigned char sm_A[65536];
  const int t = threadIdx.x;
  const int w = t >> 6, l = t & 63;
  const int hi = l >> 5, ln = l & 31;
  const int r0 = blockIdx.x * 64;
  const int ph = blockIdx.x & 31;

  {
    const unsigned char* src = t1g + (size_t)blockIdx.x * 65536;
#pragma unroll
    for (int it = 0; it < 8; ++it)
      glds16(src + it * 8192 + t * 16, sm_A + it * 8192 + t * 16);
  }

  auto loadB = [&](uint4* dst, int p) {
    int kt = (p + ph) & 31;
    const uint4* src = (const uint4*)w2ts +
        ((size_t)(2 * kt + hi) * 512 + w * 64 + ln);
    dst[0] = src[0];
    dst[1] = src[32];
  };

  f32x16 acc[4];  // [mf*2+nf]
#pragma unroll
  for (int i = 0; i < 4; ++i)
#pragma unroll
    for (int k = 0; k < 16; ++k) acc[i][k] = 0.0f;

  uint4 bb[4][2];
#pragma unroll
  for (int p = 0; p < 4; ++p) loadB(bb[p], p);
  __syncthreads();  // drains global_load_lds too

#pragma unroll
  for (int ks = 0; ks < 32; ++ks) {
    int kt = (ks + ph) & 31;
    const unsigned char* ab = sm_A + (size_t)((2 * kt + hi) * 64 + ln) * 16;
    bf16x8 a0 = *(const bf16x8*)(ab);
    bf16x8 a1 = *(const bf16x8*)(ab + 512);
#pragma unroll
    for (int nf = 0; nf < 2; ++nf) {
      bf16x8 bv = __builtin_bit_cast(bf16x8, bb[ks & 3][nf]);
      acc[0 + nf] = __builtin_amdgcn_mfma_f32_32x32x16_bf16(a0, bv, acc[0 + nf], 0, 0, 0);
      acc[2 + nf] = __builtin_amdgcn_mfma_f32_32x32x16_bf16(a1, bv, acc[2 + nf], 0, 0, 0);
    }
    if (ks < 28) loadB(bb[ks & 3], ks + 4);
  }

  if (EPI == 0) {
#pragma unroll
    for (int nf = 0; nf < 2; ++nf) {
      float s = 0.f, q = 0.f;
#pragma unroll
      for (int mf = 0; mf < 2; ++mf)
#pragma unroll
        for (int k = 0; k < 16; ++k) {
          float v = acc[mf * 2 + nf][k];
          s += v; q += v * v;
        }
      s += __shfl_xor(s, 32); q += __shfl_xor(q, 32);
      if (hi == 0) {
        int col = w * 64 + nf * 32 + ln;
        atomicAdd(&stat2[col], s);
        atomicAdd(&stat2[512 + col], q);
      }
    }
  } else {
    float sv[2], cv[2], wv[2];
#pragma unroll
    for (int nf = 0; nf < 2; ++nf) {
      int col = w * 64 + nf * 32 + ln;
      sv[nf] = s2g[col]; cv[nf] = c2g[col]; wv[nf] = w3g[col];
    }
    __syncthreads();
    float* pr = (float*)sm_A;  // [64 rows][8 waves]
#pragma unroll
    for (int mf = 0; mf < 2; ++mf)
#pragma unroll
      for (int k = 0; k < 16; ++k) {
        float v = fast_tanh(acc[mf * 2 + 0][k] * sv[0] + cv[0]) * wv[0] +
                  fast_tanh(acc[mf * 2 + 1][k] * sv[1] + cv[1]) * wv[1];
        v += __shfl_xor(v, 1); v += __shfl_xor(v, 2); v += __shfl_xor(v, 4);
        v += __shfl_xor(v, 8); v += __shfl_xor(v, 16);
        if (ln == 0) {
          int row = mf * 32 + (k & 3) + 8 * (k >> 2) + 4 * hi;
          pr[row * 8 + w] = v;
        }
      }
    __syncthreads();
    if (t < 64) {
      float s = b3g[0];
#pragma unroll
      for (int i = 0; i < 8; ++i) s += pr[t * 8 + i];
      out[r0 + t] = s;
    }
  }
}

// ---------- PATH B fallback: R6 fused gemm, verbatim (M=128, wave 128x64) ----------
template <int EPI>
__global__ __launch_bounds__(512, 2) void gemm_fb(
    const float* __restrict__ x, const float* __restrict__ tsg,
    const float* __restrict__ teg, const float* __restrict__ tbg,
    const unsigned char* __restrict__ a1img,
    const unsigned char* __restrict__ w2ts, float* __restrict__ stat2,
    const float* __restrict__ s2g, const float* __restrict__ c2g,
    const float* __restrict__ w3g, const float* __restrict__ b3g,
    float* __restrict__ out) {
  __shared__ __align__(16) unsigned char sm_buf[2][32768];
  __shared__ __align__(16) float sm_u[128][4];
  __shared__ float sm_ts[9], sm_te[14], sm_tb[126];

  const int t = threadIdx.x;
  const int w = t >> 6, l = t & 63;
  const int hi = l >> 5, ln = l & 31;
  const int rt = w & 3;
  const int jtp = (w >> 2) * 2;
  const int r0 = blockIdx.x * 128;

  if (t < 9) sm_ts[t] = tsg[t];
  if (t < 14) sm_te[t] = teg[t];
  if (t < 126) sm_tb[t] = tbg[t];
  __syncthreads();
  if (t < 128) {
    const float* xr = x + (size_t)(r0 + t) * 15;
    float amb = xr[1], inc = xr[8];
    sm_u[t][0] = inter2d_d(sm_ts, sm_te, sm_tb, xr[2], amb) - inc;
    sm_u[t][1] = inter2d_d(sm_ts, sm_te, sm_tb, xr[3], amb) - inc;
    sm_u[t][2] = amb;
    sm_u[t][3] = xr[9] - xr[10];
  }
  __syncthreads();

  bf16x8 uf;
  {
    float4 uv = *(const float4*)&sm_u[rt * 32 + ln][0];
    u16 b0_ = f2bf(uv.x), b1_ = f2bf(uv.y), b2_ = f2bf(uv.z), b3_ = f2bf(uv.w);
    u32x4 uq;
    if (hi == 0) {
      uq[0] = (u32)b0_ | ((u32)b1_ << 16);
      uq[1] = (u32)b2_ | ((u32)b3_ << 16);
      uq[2] = 0x00003F80u | ((u32)b0_ << 16);
      uq[3] = (u32)b1_ | ((u32)b2_ << 16);
    } else {
      u16 d0 = f2bf(uv.x - bf2f(b0_)), d1 = f2bf(uv.y - bf2f(b1_));
      u16 d2 = f2bf(uv.z - bf2f(b2_)), d3 = f2bf(uv.w - bf2f(b3_));
      uq[0] = (u32)d0 | ((u32)d1 << 16);
      uq[1] = (u32)d2 | ((u32)d3 << 16);
      uq[2] = 0x00003F80u | ((u32)b3_ << 16);
      uq[3] = 0u;
    }
    uf = __builtin_bit_cast(bf16x8, uq);
  }

  auto produce = [&](int sl, unsigned char* dst) {
#pragma unroll
    for (int i = 0; i < 2; ++i) {
      int jt = jtp + i;
      bf16x8 af = *(const bf16x8*)(a1img +
          ((size_t)(sl * 128 + jt * 32 + ln) * 32 + hi * 16));
      f32x16 z = {};
      f32x16 d = __builtin_amdgcn_mfma_f32_32x32x16_bf16(af, uf, z, 0, 0, 0);
#pragma unroll
      for (int q = 0; q < 4; ++q) {
        u32 plo = pack2bf(fast_tanh(d[q * 4 + 0]), fast_tanh(d[q * 4 + 1]));
        u32 phi = pack2bf(fast_tanh(d[q * 4 + 2]), fast_tanh(d[q * 4 + 3]));
        *(uint2*)(dst + ((size_t)((jt * 4 + q) * 128 + rt * 32 + ln) * 16 + hi * 8)) =
            make_uint2(plo, phi);
      }
    }
  };

  auto loadB = [&](uint4* dst, int ks) {
    const unsigned char* p = w2ts + ((size_t)(ks * 2 + hi) * 8192) +
                             (size_t)(w * 64 + ln) * 16;
    dst[0] = *(const uint4*)(p);
    dst[1] = *(const uint4*)(p + 512);
  };

  f32x16 acc[8];  // [mf*2+nf], 4 m-frags x 2 n-frags (wave tile 128x64)
#pragma unroll
  for (int i = 0; i < 8; ++i)
#pragma unroll
    for (int k = 0; k < 16; ++k) acc[i][k] = 0.0f;

  produce(0, sm_buf[0]);
  uint4 bb[2][2];
  loadB(bb[0], 0);
  __syncthreads();

#pragma unroll
  for (int sl = 0; sl < 4; ++sl) {
    const unsigned char* abuf = sm_buf[sl & 1];
#pragma unroll
    for (int s = 0; s < 8; ++s) {
      int ks = sl * 8 + s;
      if (ks < 31) loadB(bb[(s + 1) & 1], ks + 1);
      const unsigned char* ab = abuf + ((size_t)(2 * s + hi) * 128 + ln) * 16;
      bf16x8 a0 = *(const bf16x8*)(ab);
      bf16x8 a1 = *(const bf16x8*)(ab + 512);
      bf16x8 a2 = *(const bf16x8*)(ab + 1024);
      bf16x8 a3 = *(const bf16x8*)(ab + 1536);
#pragma unroll
      for (int nf = 0; nf < 2; ++nf) {
        bf16x8 bv = __builtin_bit_cast(bf16x8, bb[s & 1][nf]);
        acc[0 + nf] = __builtin_amdgcn_mfma_f32_32x32x16_bf16(a0, bv, acc[0 + nf], 0, 0, 0);
        acc[2 + nf] = __builtin_amdgcn_mfma_f32_32x32x16_bf16(a1, bv, acc[2 + nf], 0, 0, 0);
        acc[4 + nf] = __builtin_amdgcn_mfma_f32_32x32x16_bf16(a2, bv, acc[4 + nf], 0, 0, 0);
        acc[6 + nf] = __builtin_amdgcn_mfma_f32_32x32x16_bf16(a3, bv, acc[6 + nf], 0, 0, 0);
      }
      if (s == 0 && sl < 3) produce(sl + 1, sm_buf[(sl + 1) & 1]);
    }
    __syncthreads();
  }

  if (EPI == 0) {
#pragma unroll
    for (int nf = 0; nf < 2; ++nf) {
      float s = 0.f, q = 0.f;
#pragma unroll
      for (int mf = 0; mf < 4; ++mf)
#pragma unroll
        for (int k = 0; k < 16; ++k) {
          float v = acc[mf * 2 + nf][k];
          s += v; q += v * v;
        }
      s += __shfl_xor(s, 32); q += __shfl_xor(q, 32);
      if (hi == 0) {
        int col = w * 64 + nf * 32 + ln;
        atomicAdd(&stat2[col], s);
        atomicAdd(&stat2[512 + col], q);
      }
    }
  } else {
    float sv[2], cv[2], wv[2];
#pragma unroll
    for (int nf = 0; nf < 2; ++nf) {
      int col = w * 64 + nf * 32 + ln;
      sv[nf] = s2g[col]; cv[nf] = c2g[col]; wv[nf] = w3g[col];
    }
    float* pr = (float*)sm_buf[0];  // [128 rows][8 waves]
#pragma unroll
    for (int mf = 0; mf < 4; ++mf)
#pragma unroll
      for (int k = 0; k < 16; ++k) {
        float v = fast_tanh(acc[mf * 2 + 0][k] * sv[0] + cv[0]) * wv[0] +
                  fast_tanh(acc[mf * 2 + 1][k] * sv[1] + cv[1]) * wv[1];
        v += __shfl_xor(v, 1); v += __shfl_xor(v, 2); v += __shfl_xor(v, 4);
        v += __shfl_xor(v, 8); v += __shfl_xor(v, 16);
        if (ln == 0) {
          int row = mf * 32 + (k & 3) + 8 * (k >> 2) + 4 * hi;
          pr[row * 8 + w] = v;
        }
      }
    __syncthreads();
    if (t < 128) {
      float s = b3g[0];
#pragma unroll
      for (int i = 0; i < 8; ++i) s += pr[t * 8 + i];
      out[r0 + t] = s;
    }
  }
}

// ---------- launcher ----------
extern "C" void kernel_launch(void* const* d_in, const int* in_sizes, int n_in,
                              void* d_out, int out_size, void* d_ws, size_t ws_size,
                              hipStream_t stream) {
  const float* x   = (const float*)d_in[0];
  const float* ts  = (const float*)d_in[1];
  const float* te  = (const float*)d_in[2];
  const float* tab = (const float*)d_in[3];
  const float* w1  = (const float*)d_in[4];
  const float* g1  = (const float*)d_in[6];
  const float* be1 = (const float*)d_in[7];
  const float* w2  = (const float*)d_in[8];
  const float* g2  = (const float*)d_in[10];
  const float* be2 = (const float*)d_in[11];
  const float* w3  = (const float*)d_in[12];
  const float* b3  = (const float*)d_in[13];
  float* out = (float*)d_out;
  char* ws = (char*)d_ws;

  if (ws_size < (size_t)(32768 + 524288)) return;

  int Bn = in_sizes[0] / 15;  // 262144
  float invB = 1.0f / (float)Bn;

  float* mom   = (float*)(ws + 0);
  float* stat2 = (float*)(ws + 64);
  unsigned char* a1img = (unsigned char*)(ws + 4160);   // 16 KB
  float* s2    = (float*)(ws + 20544);
  float* c2    = (float*)(ws + 22592);
  unsigned char* w2ts = (unsigned char*)(ws + 32768);   // 512 KB
  unsigned char* t1g  = (unsigned char*)(ws + 1048576); // 268 MB (path A)

  const size_t needA = 1048576 + (size_t)Bn * 512 * 2;
  const bool bigWs = (ws_size >= needA);

  (void)hipMemsetAsync(ws, 0, 4160, stream);
  stats1_kernel<<<Bn / 256, 256, 0, stream>>>(x, ts, te, tab, mom);
  prep1_kernel<<<1, 512, 0, stream>>>(mom, w1, g1, be1, a1img, invB);
  transpose_w2<<<128, 256, 0, stream>>>(w2, w2ts);

  if (bigWs) {
    produce_t1<<<Bn / 64, 256, 0, stream>>>(x, ts, te, tab, a1img, t1g);
    gemm_pure<0><<<Bn / 64, 512, 0, stream>>>(t1g, w2ts, stat2,
                                              nullptr, nullptr, nullptr, nullptr, nullptr);
    prep2_kernel<<<1, 512, 0, stream>>>(stat2, g2, be2, s2, c2, invB);
    gemm_pure<1><<<Bn / 64, 512, 0, stream>>>(t1g, w2ts, stat2,
                                              s2, c2, w3, b3, out);
  } else {
    gemm_fb<0><<<Bn / 128, 512, 0, stream>>>(x, ts, te, tab, a1img, w2ts, stat2,
                                             nullptr, nullptr, nullptr, nullptr, nullptr);
    prep2_kernel<<<1, 512, 0, stream>>>(stat2, g2, be2, s2, c2, invB);
    gemm_fb<1><<<Bn / 128, 512, 0, stream>>>(x, ts, te, tab, a1img, w2ts, stat2,
                                             s2, c2, w3, b3, out);
  }
}